// Round 11
// baseline (29.554 us; speedup 1.0000x reference)
//
#include <hip/hip_runtime.h>

// out[b,o,ds] = sum_i x[b,i] * peso[o,i,ds] for i where mask[o,i]==1
// B=256, IN=1024, OUT=512, DS=128, ~10% (o,i) kept; mask values exactly {0,1}.
//
// MFMA v5: v4 (T10 tr-read staging) + float4 epilogue via LDS bounce +
// hoisted sidx. Main loop / fragment path identical to the verified R10.

#define B_    256
#define IN_   1024
#define OUT_  512
#define DS_   128
#define SLAB  1024                 // one [32 k][16] bf16 slab, 128-B aligned
#define CHB   (8 * SLAB)           // 8 KiB per operand chunk tile (32 k x 128)
#define EPITCH 132                 // epilogue LDS pitch in words (528 B rows)

typedef float        f32x4    __attribute__((ext_vector_type(4)));
typedef short        short8   __attribute__((ext_vector_type(8)));
typedef unsigned int uint32x2 __attribute__((ext_vector_type(2)));
typedef unsigned int uint32x4 __attribute__((ext_vector_type(4)));

static __device__ __forceinline__ unsigned f2bf(float f) {
    unsigned u = __builtin_bit_cast(unsigned, f);
    u = u + 0x7fff + ((u >> 16) & 1);          // RNE
    return u >> 16;
}

// ws layout:
//   [0, 512 KiB)            xTbf ushort[IN_][B_]  (bf16)
//   [1 MiB, +2 KiB)         cnt  int[OUT_]
//   [1 MiB + 4 KiB, +2 MiB) idx  int[OUT_][IN_]

__global__ __launch_bounds__(256) void prep_kernel(const float* __restrict__ x,
                                                   unsigned short* __restrict__ xTbf,
                                                   const float* __restrict__ mask,
                                                   int* __restrict__ cnt,
                                                   int* __restrict__ idx) {
    __shared__ float tile[64][65];
    __shared__ int   wsum[4];
    int bid = blockIdx.x;
    int t   = threadIdx.x;

    if (bid < 64) {                            // ---- transpose x -> bf16 xT ----
        int c  = t & 63;
        int r0 = t >> 6;
        int i0 = (bid & 15) * 64;
        int b0 = (bid >> 4) * 64;
#pragma unroll
        for (int k = 0; k < 16; ++k) {
            int r = r0 + k * 4;
            tile[r][c] = x[(size_t)(b0 + r) * IN_ + i0 + c];
        }
        __syncthreads();
#pragma unroll
        for (int k = 0; k < 16; ++k) {
            int r = r0 + k * 4;
            xTbf[(size_t)(i0 + r) * B_ + b0 + c] = (unsigned short)f2bf(tile[c][r]);
        }
    } else {                                   // ---- compact mask row o ----
        int o    = bid - 64;
        int lane = t & 63;
        int wv   = t >> 6;
        const float* mrow = mask + (size_t)o * IN_;

        int loc[4];
        int c = 0;
        int ibase = t * 4;
#pragma unroll
        for (int k = 0; k < 4; ++k) {
            if (mrow[ibase + k] != 0.0f) loc[c++] = ibase + k;
        }
        int v = c;
#pragma unroll
        for (int off = 1; off < 64; off <<= 1) {
            int u = __shfl_up(v, off, 64);
            if (lane >= off) v += u;
        }
        if (lane == 63) wsum[wv] = v;
        __syncthreads();
        int base = 0;
        for (int w = 0; w < wv; ++w) base += wsum[w];
        int excl = base + v - c;

        int* orow = idx + (size_t)o * IN_;
        for (int k = 0; k < c; ++k) orow[excl + k] = loc[k];
        if (t == 255) cnt[o] = base + v;
    }
}

__global__ __launch_bounds__(512) void spmm_mfma(const unsigned short* __restrict__ xTbf,
                                                 const float* __restrict__ peso,
                                                 const int* __restrict__ cnt,
                                                 const int* __restrict__ idx,
                                                 float* __restrict__ out) {
    __shared__ __align__(16) char smem[36864];
    char* xa   = smem;                         // A: 2 chunks x 8 slabs [32k][16b]
    char* wt   = smem + 2 * CHB;               // B: 2 chunks x 8 slabs [32k][16ds]
    int*  sidx = (int*)(smem + 4 * CHB);       // [1024]

    int bid  = blockIdx.x;
    int c8   = bid & 7;                        // XCD id (round-robin dispatch)
    int m    = bid >> 3;
    int o    = (m >> 1) * 8 + c8;              // both halves of an o -> same XCD
    int half = m & 1;
    int t    = threadIdx.x;
    int lane = t & 63;
    int wv   = __builtin_amdgcn_readfirstlane(t >> 6);
    int wr   = wv & 3;                         // row group: 32 b-rows
    int wc   = wv >> 2;                        // col group: 64 ds-cols

    int n = cnt[o];
    const int* irow = idx + (size_t)o * IN_;
    for (int f = t; f < n; f += 512) sidx[f] = irow[f];   // hoisted, coalesced
    __syncthreads();

    int kk = t >> 4;                           // staging k-row 0..31
    int q  = t & 15;                           // quad id (covers q and q+16)
    const char* wbase = (const char*)(peso + (size_t)o * IN_ * DS_) + q * 16;
    const char* xbase = (const char*)xTbf + half * 256 + q * 8;
    int st_off = kk * 32 + 8 * (q & 3);        // byte offset within a slab row set

    unsigned xa0 = (unsigned)(uintptr_t)(void*)xa + lane * 8;
    unsigned wt0 = (unsigned)(uintptr_t)(void*)wt + lane * 8;

    f32x4 acc[2][4];
#pragma unroll
    for (int a = 0; a < 2; ++a)
#pragma unroll
        for (int b = 0; b < 4; ++b) acc[a][b] = (f32x4){0.f, 0.f, 0.f, 0.f};

    for (int k0 = 0; k0 < n; k0 += 64) {
        if (k0) __syncthreads();               // prev MFMA readers done
        int nch = (n - k0 > 32) ? 2 : 1;
        int g0 = k0 + kk, g1 = k0 + 32 + kk;
        int ok0 = g0 < n, ok1 = g1 < n;
        int id0 = sidx[ok0 ? g0 : 0];
        int id1 = sidx[ok1 ? g1 : 0];
        size_t r0 = (size_t)(ok0 ? id0 : 0);
        size_t r1 = (size_t)(ok1 ? id1 : 0);

        // ---- issue ALL global loads (both chunks) before any use ----
        f32x4   w0a = *(const f32x4*)(wbase + r0 * 512);
        f32x4   w0b = *(const f32x4*)(wbase + r0 * 512 + 256);
        ushort4 x0a = *(const ushort4*)(xbase + r0 * 512);
        ushort4 x0b = *(const ushort4*)(xbase + r0 * 512 + 128);
        f32x4   w1a = *(const f32x4*)(wbase + r1 * 512);
        f32x4   w1b = *(const f32x4*)(wbase + r1 * 512 + 256);
        ushort4 x1a = *(const ushort4*)(xbase + r1 * 512);
        ushort4 x1b = *(const ushort4*)(xbase + r1 * 512 + 128);

        // ---- convert + aligned b64 LDS writes (natural [k][*16] slabs) ----
#define PUT(dst_, chunk_, slab_, pw_)                                       \
        *(uint32x2*)((dst_) + (chunk_) * CHB + (slab_) * SLAB + st_off) = (pw_)
        {
            uint32x2 pw, px;
            pw = (uint32x2){f2bf(w0a.x) | (f2bf(w0a.y) << 16),
                            f2bf(w0a.z) | (f2bf(w0a.w) << 16)};
            if (!ok0) pw = (uint32x2){0, 0};
            PUT(wt, 0, (q >> 2), pw);
            pw = (uint32x2){f2bf(w0b.x) | (f2bf(w0b.y) << 16),
                            f2bf(w0b.z) | (f2bf(w0b.w) << 16)};
            if (!ok0) pw = (uint32x2){0, 0};
            PUT(wt, 0, (q >> 2) + 4, pw);
            px = (uint32x2){(unsigned)x0a.x | ((unsigned)x0a.y << 16),
                            (unsigned)x0a.z | ((unsigned)x0a.w << 16)};
            if (!ok0) px = (uint32x2){0, 0};
            PUT(xa, 0, (q >> 2), px);
            px = (uint32x2){(unsigned)x0b.x | ((unsigned)x0b.y << 16),
                            (unsigned)x0b.z | ((unsigned)x0b.w << 16)};
            if (!ok0) px = (uint32x2){0, 0};
            PUT(xa, 0, (q >> 2) + 4, px);
        }
        if (nch == 2) {
            uint32x2 pw, px;
            pw = (uint32x2){f2bf(w1a.x) | (f2bf(w1a.y) << 16),
                            f2bf(w1a.z) | (f2bf(w1a.w) << 16)};
            if (!ok1) pw = (uint32x2){0, 0};
            PUT(wt, 1, (q >> 2), pw);
            pw = (uint32x2){f2bf(w1b.x) | (f2bf(w1b.y) << 16),
                            f2bf(w1b.z) | (f2bf(w1b.w) << 16)};
            if (!ok1) pw = (uint32x2){0, 0};
            PUT(wt, 1, (q >> 2) + 4, pw);
            px = (uint32x2){(unsigned)x1a.x | ((unsigned)x1a.y << 16),
                            (unsigned)x1a.z | ((unsigned)x1a.w << 16)};
            if (!ok1) px = (uint32x2){0, 0};
            PUT(xa, 1, (q >> 2), px);
            px = (uint32x2){(unsigned)x1b.x | ((unsigned)x1b.y << 16),
                            (unsigned)x1b.z | ((unsigned)x1b.w << 16)};
            if (!ok1) px = (uint32x2){0, 0};
            PUT(xa, 1, (q >> 2) + 4, px);
        }
#undef PUT
        __syncthreads();                       // tiles ready

        // ---- MFMA via hardware transpose reads ----
        for (int c = 0; c < nch; ++c) {
            uint32x2 al[2], ah[2], bl[4], bh[4];
#pragma unroll
            for (int rt = 0; rt < 2; ++rt) {
                unsigned ad = xa0 + c * CHB + (wr * 2 + rt) * SLAB;
                asm volatile("ds_read_b64_tr_b16 %0, %1"
                             : "=v"(al[rt]) : "v"(ad));
                asm volatile("ds_read_b64_tr_b16 %0, %1 offset:512"
                             : "=v"(ah[rt]) : "v"(ad));
            }
#pragma unroll
            for (int ct = 0; ct < 4; ++ct) {
                unsigned bd = wt0 + c * CHB + (wc * 4 + ct) * SLAB;
                asm volatile("ds_read_b64_tr_b16 %0, %1"
                             : "=v"(bl[ct]) : "v"(bd));
                asm volatile("ds_read_b64_tr_b16 %0, %1 offset:512"
                             : "=v"(bh[ct]) : "v"(bd));
            }
            asm volatile("s_waitcnt lgkmcnt(0)" ::: "memory");
            __builtin_amdgcn_sched_barrier(0);

            short8 afr[2], bfr[4];
#pragma unroll
            for (int rt = 0; rt < 2; ++rt)
                afr[rt] = __builtin_bit_cast(short8,
                    (uint32x4){al[rt].x, al[rt].y, ah[rt].x, ah[rt].y});
#pragma unroll
            for (int ct = 0; ct < 4; ++ct)
                bfr[ct] = __builtin_bit_cast(short8,
                    (uint32x4){bl[ct].x, bl[ct].y, bh[ct].x, bh[ct].y});
#pragma unroll
            for (int rt = 0; rt < 2; ++rt)
#pragma unroll
                for (int ct = 0; ct < 4; ++ct)
                    acc[rt][ct] = __builtin_amdgcn_mfma_f32_16x16x32_bf16(
                        afr[rt], bfr[ct], acc[rt][ct], 0, 0, 0);
        }
    }

    // ---- epilogue: LDS bounce -> float4 coalesced stores ----
    // C/D layout (m89): col = lane&15, row = (lane>>4)*4 + q
    float* ep = (float*)smem;                  // alias staging LDS (33 KB)
    __syncthreads();                           // main-loop LDS reads done
#pragma unroll
    for (int r = 0; r < 2; ++r) {
        if ((wr >> 1) == r) {
            int lr0 = (wr & 1) * 32 + ((lane >> 4) << 2);
            int ds0 = wc * 64 + (lane & 15);
#pragma unroll
            for (int rt = 0; rt < 2; ++rt)
#pragma unroll
                for (int ct = 0; ct < 4; ++ct)
#pragma unroll
                    for (int qq = 0; qq < 4; ++qq)
                        ep[(lr0 + rt * 16 + qq) * EPITCH + ds0 + ct * 16]
                            = acc[rt][ct][qq];
        }
        __syncthreads();
        float* orow0 = out + (size_t)(half * 128 + r * 64) * (OUT_ * DS_) + o * DS_;
#pragma unroll
        for (int k = 0; k < 4; ++k) {
            int f   = t + 512 * k;             // 0..2047
            int row = f >> 5;
            int c4  = f & 31;
            f32x4 v = *(const f32x4*)(ep + row * EPITCH + c4 * 4);
            *(f32x4*)(orow0 + (size_t)row * (OUT_ * DS_) + c4 * 4) = v;
        }
        if (r == 0) __syncthreads();
    }
}

extern "C" void kernel_launch(void* const* d_in, const int* in_sizes, int n_in,
                              void* d_out, int out_size, void* d_ws, size_t ws_size,
                              hipStream_t stream) {
    const float* x    = (const float*)d_in[0];
    const float* peso = (const float*)d_in[1];
    const float* mask = (const float*)d_in[2];
    float* out = (float*)d_out;

    char* ws = (char*)d_ws;
    unsigned short* xTbf = (unsigned short*)ws;
    int*            cnt  = (int*)(ws + (1 << 20));
    int*            idx  = (int*)(ws + (1 << 20) + 4096);

    prep_kernel<<<64 + OUT_, 256, 0, stream>>>(x, xTbf, mask, cnt, idx);
    spmm_mfma<<<OUT_ * 2, 512, 0, stream>>>(xTbf, peso, cnt, idx, out);
}

// Round 12
// 28.055 us; speedup vs baseline: 1.0534x; 1.0534x over previous
//
#include <hip/hip_runtime.h>

// out[b,o,ds] = sum_i x[b,i] * peso[o,i,ds] for i where mask[o,i]==1
// B=256, IN=1024, OUT=512, DS=128, ~10% (o,i) kept; mask values exactly {0,1}.
//
// MFMA v6: identical to v5 (T10 tr-read staging, float4 epilogue via LDS
// bounce, hoisted sidx) EXCEPT the output stores are nontemporal (output is
// write-once; keep L2 for peso rows + the hot xT table).

#define B_    256
#define IN_   1024
#define OUT_  512
#define DS_   128
#define SLAB  1024                 // one [32 k][16] bf16 slab, 128-B aligned
#define CHB   (8 * SLAB)           // 8 KiB per operand chunk tile (32 k x 128)
#define EPITCH 132                 // epilogue LDS pitch in words (528 B rows)

typedef float        f32x4    __attribute__((ext_vector_type(4)));
typedef short        short8   __attribute__((ext_vector_type(8)));
typedef unsigned int uint32x2 __attribute__((ext_vector_type(2)));
typedef unsigned int uint32x4 __attribute__((ext_vector_type(4)));

static __device__ __forceinline__ unsigned f2bf(float f) {
    unsigned u = __builtin_bit_cast(unsigned, f);
    u = u + 0x7fff + ((u >> 16) & 1);          // RNE
    return u >> 16;
}

// ws layout:
//   [0, 512 KiB)            xTbf ushort[IN_][B_]  (bf16)
//   [1 MiB, +2 KiB)         cnt  int[OUT_]
//   [1 MiB + 4 KiB, +2 MiB) idx  int[OUT_][IN_]

__global__ __launch_bounds__(256) void prep_kernel(const float* __restrict__ x,
                                                   unsigned short* __restrict__ xTbf,
                                                   const float* __restrict__ mask,
                                                   int* __restrict__ cnt,
                                                   int* __restrict__ idx) {
    __shared__ float tile[64][65];
    __shared__ int   wsum[4];
    int bid = blockIdx.x;
    int t   = threadIdx.x;

    if (bid < 64) {                            // ---- transpose x -> bf16 xT ----
        int c  = t & 63;
        int r0 = t >> 6;
        int i0 = (bid & 15) * 64;
        int b0 = (bid >> 4) * 64;
#pragma unroll
        for (int k = 0; k < 16; ++k) {
            int r = r0 + k * 4;
            tile[r][c] = x[(size_t)(b0 + r) * IN_ + i0 + c];
        }
        __syncthreads();
#pragma unroll
        for (int k = 0; k < 16; ++k) {
            int r = r0 + k * 4;
            xTbf[(size_t)(i0 + r) * B_ + b0 + c] = (unsigned short)f2bf(tile[c][r]);
        }
    } else {                                   // ---- compact mask row o ----
        int o    = bid - 64;
        int lane = t & 63;
        int wv   = t >> 6;
        const float* mrow = mask + (size_t)o * IN_;

        int loc[4];
        int c = 0;
        int ibase = t * 4;
#pragma unroll
        for (int k = 0; k < 4; ++k) {
            if (mrow[ibase + k] != 0.0f) loc[c++] = ibase + k;
        }
        int v = c;
#pragma unroll
        for (int off = 1; off < 64; off <<= 1) {
            int u = __shfl_up(v, off, 64);
            if (lane >= off) v += u;
        }
        if (lane == 63) wsum[wv] = v;
        __syncthreads();
        int base = 0;
        for (int w = 0; w < wv; ++w) base += wsum[w];
        int excl = base + v - c;

        int* orow = idx + (size_t)o * IN_;
        for (int k = 0; k < c; ++k) orow[excl + k] = loc[k];
        if (t == 255) cnt[o] = base + v;
    }
}

__global__ __launch_bounds__(512) void spmm_mfma(const unsigned short* __restrict__ xTbf,
                                                 const float* __restrict__ peso,
                                                 const int* __restrict__ cnt,
                                                 const int* __restrict__ idx,
                                                 float* __restrict__ out) {
    __shared__ __align__(16) char smem[36864];
    char* xa   = smem;                         // A: 2 chunks x 8 slabs [32k][16b]
    char* wt   = smem + 2 * CHB;               // B: 2 chunks x 8 slabs [32k][16ds]
    int*  sidx = (int*)(smem + 4 * CHB);       // [1024]

    int bid  = blockIdx.x;
    int c8   = bid & 7;                        // XCD id (round-robin dispatch)
    int m    = bid >> 3;
    int o    = (m >> 1) * 8 + c8;              // both halves of an o -> same XCD
    int half = m & 1;
    int t    = threadIdx.x;
    int lane = t & 63;
    int wv   = __builtin_amdgcn_readfirstlane(t >> 6);
    int wr   = wv & 3;                         // row group: 32 b-rows
    int wc   = wv >> 2;                        // col group: 64 ds-cols

    int n = cnt[o];
    const int* irow = idx + (size_t)o * IN_;
    for (int f = t; f < n; f += 512) sidx[f] = irow[f];   // hoisted, coalesced
    __syncthreads();

    int kk = t >> 4;                           // staging k-row 0..31
    int q  = t & 15;                           // quad id (covers q and q+16)
    const char* wbase = (const char*)(peso + (size_t)o * IN_ * DS_) + q * 16;
    const char* xbase = (const char*)xTbf + half * 256 + q * 8;
    int st_off = kk * 32 + 8 * (q & 3);        // byte offset within a slab row set

    unsigned xa0 = (unsigned)(uintptr_t)(void*)xa + lane * 8;
    unsigned wt0 = (unsigned)(uintptr_t)(void*)wt + lane * 8;

    f32x4 acc[2][4];
#pragma unroll
    for (int a = 0; a < 2; ++a)
#pragma unroll
        for (int b = 0; b < 4; ++b) acc[a][b] = (f32x4){0.f, 0.f, 0.f, 0.f};

    for (int k0 = 0; k0 < n; k0 += 64) {
        if (k0) __syncthreads();               // prev MFMA readers done
        int nch = (n - k0 > 32) ? 2 : 1;
        int g0 = k0 + kk, g1 = k0 + 32 + kk;
        int ok0 = g0 < n, ok1 = g1 < n;
        int id0 = sidx[ok0 ? g0 : 0];
        int id1 = sidx[ok1 ? g1 : 0];
        size_t r0 = (size_t)(ok0 ? id0 : 0);
        size_t r1 = (size_t)(ok1 ? id1 : 0);

        // ---- issue ALL global loads (both chunks) before any use ----
        f32x4   w0a = *(const f32x4*)(wbase + r0 * 512);
        f32x4   w0b = *(const f32x4*)(wbase + r0 * 512 + 256);
        ushort4 x0a = *(const ushort4*)(xbase + r0 * 512);
        ushort4 x0b = *(const ushort4*)(xbase + r0 * 512 + 128);
        f32x4   w1a = *(const f32x4*)(wbase + r1 * 512);
        f32x4   w1b = *(const f32x4*)(wbase + r1 * 512 + 256);
        ushort4 x1a = *(const ushort4*)(xbase + r1 * 512);
        ushort4 x1b = *(const ushort4*)(xbase + r1 * 512 + 128);

        // ---- convert + aligned b64 LDS writes (natural [k][*16] slabs) ----
#define PUT(dst_, chunk_, slab_, pw_)                                       \
        *(uint32x2*)((dst_) + (chunk_) * CHB + (slab_) * SLAB + st_off) = (pw_)
        {
            uint32x2 pw, px;
            pw = (uint32x2){f2bf(w0a.x) | (f2bf(w0a.y) << 16),
                            f2bf(w0a.z) | (f2bf(w0a.w) << 16)};
            if (!ok0) pw = (uint32x2){0, 0};
            PUT(wt, 0, (q >> 2), pw);
            pw = (uint32x2){f2bf(w0b.x) | (f2bf(w0b.y) << 16),
                            f2bf(w0b.z) | (f2bf(w0b.w) << 16)};
            if (!ok0) pw = (uint32x2){0, 0};
            PUT(wt, 0, (q >> 2) + 4, pw);
            px = (uint32x2){(unsigned)x0a.x | ((unsigned)x0a.y << 16),
                            (unsigned)x0a.z | ((unsigned)x0a.w << 16)};
            if (!ok0) px = (uint32x2){0, 0};
            PUT(xa, 0, (q >> 2), px);
            px = (uint32x2){(unsigned)x0b.x | ((unsigned)x0b.y << 16),
                            (unsigned)x0b.z | ((unsigned)x0b.w << 16)};
            if (!ok0) px = (uint32x2){0, 0};
            PUT(xa, 0, (q >> 2) + 4, px);
        }
        if (nch == 2) {
            uint32x2 pw, px;
            pw = (uint32x2){f2bf(w1a.x) | (f2bf(w1a.y) << 16),
                            f2bf(w1a.z) | (f2bf(w1a.w) << 16)};
            if (!ok1) pw = (uint32x2){0, 0};
            PUT(wt, 1, (q >> 2), pw);
            pw = (uint32x2){f2bf(w1b.x) | (f2bf(w1b.y) << 16),
                            f2bf(w1b.z) | (f2bf(w1b.w) << 16)};
            if (!ok1) pw = (uint32x2){0, 0};
            PUT(wt, 1, (q >> 2) + 4, pw);
            px = (uint32x2){(unsigned)x1a.x | ((unsigned)x1a.y << 16),
                            (unsigned)x1a.z | ((unsigned)x1a.w << 16)};
            if (!ok1) px = (uint32x2){0, 0};
            PUT(xa, 1, (q >> 2), px);
            px = (uint32x2){(unsigned)x1b.x | ((unsigned)x1b.y << 16),
                            (unsigned)x1b.z | ((unsigned)x1b.w << 16)};
            if (!ok1) px = (uint32x2){0, 0};
            PUT(xa, 1, (q >> 2) + 4, px);
        }
#undef PUT
        __syncthreads();                       // tiles ready

        // ---- MFMA via hardware transpose reads ----
        for (int c = 0; c < nch; ++c) {
            uint32x2 al[2], ah[2], bl[4], bh[4];
#pragma unroll
            for (int rt = 0; rt < 2; ++rt) {
                unsigned ad = xa0 + c * CHB + (wr * 2 + rt) * SLAB;
                asm volatile("ds_read_b64_tr_b16 %0, %1"
                             : "=v"(al[rt]) : "v"(ad));
                asm volatile("ds_read_b64_tr_b16 %0, %1 offset:512"
                             : "=v"(ah[rt]) : "v"(ad));
            }
#pragma unroll
            for (int ct = 0; ct < 4; ++ct) {
                unsigned bd = wt0 + c * CHB + (wc * 4 + ct) * SLAB;
                asm volatile("ds_read_b64_tr_b16 %0, %1"
                             : "=v"(bl[ct]) : "v"(bd));
                asm volatile("ds_read_b64_tr_b16 %0, %1 offset:512"
                             : "=v"(bh[ct]) : "v"(bd));
            }
            asm volatile("s_waitcnt lgkmcnt(0)" ::: "memory");
            __builtin_amdgcn_sched_barrier(0);

            short8 afr[2], bfr[4];
#pragma unroll
            for (int rt = 0; rt < 2; ++rt)
                afr[rt] = __builtin_bit_cast(short8,
                    (uint32x4){al[rt].x, al[rt].y, ah[rt].x, ah[rt].y});
#pragma unroll
            for (int ct = 0; ct < 4; ++ct)
                bfr[ct] = __builtin_bit_cast(short8,
                    (uint32x4){bl[ct].x, bl[ct].y, bh[ct].x, bh[ct].y});
#pragma unroll
            for (int rt = 0; rt < 2; ++rt)
#pragma unroll
                for (int ct = 0; ct < 4; ++ct)
                    acc[rt][ct] = __builtin_amdgcn_mfma_f32_16x16x32_bf16(
                        afr[rt], bfr[ct], acc[rt][ct], 0, 0, 0);
        }
    }

    // ---- epilogue: LDS bounce -> float4 NONTEMPORAL coalesced stores ----
    // C/D layout (m89): col = lane&15, row = (lane>>4)*4 + q
    float* ep = (float*)smem;                  // alias staging LDS (33 KB)
    __syncthreads();                           // main-loop LDS reads done
#pragma unroll
    for (int r = 0; r < 2; ++r) {
        if ((wr >> 1) == r) {
            int lr0 = (wr & 1) * 32 + ((lane >> 4) << 2);
            int ds0 = wc * 64 + (lane & 15);
#pragma unroll
            for (int rt = 0; rt < 2; ++rt)
#pragma unroll
                for (int ct = 0; ct < 4; ++ct)
#pragma unroll
                    for (int qq = 0; qq < 4; ++qq)
                        ep[(lr0 + rt * 16 + qq) * EPITCH + ds0 + ct * 16]
                            = acc[rt][ct][qq];
        }
        __syncthreads();
        float* orow0 = out + (size_t)(half * 128 + r * 64) * (OUT_ * DS_) + o * DS_;
#pragma unroll
        for (int k = 0; k < 4; ++k) {
            int f   = t + 512 * k;             // 0..2047
            int row = f >> 5;
            int c4  = f & 31;
            f32x4 v = *(const f32x4*)(ep + row * EPITCH + c4 * 4);
            __builtin_nontemporal_store(v,
                (f32x4*)(orow0 + (size_t)row * (OUT_ * DS_) + c4 * 4));
        }
        if (r == 0) __syncthreads();
    }
}

extern "C" void kernel_launch(void* const* d_in, const int* in_sizes, int n_in,
                              void* d_out, int out_size, void* d_ws, size_t ws_size,
                              hipStream_t stream) {
    const float* x    = (const float*)d_in[0];
    const float* peso = (const float*)d_in[1];
    const float* mask = (const float*)d_in[2];
    float* out = (float*)d_out;

    char* ws = (char*)d_ws;
    unsigned short* xTbf = (unsigned short*)ws;
    int*            cnt  = (int*)(ws + (1 << 20));
    int*            idx  = (int*)(ws + (1 << 20) + 4096);

    prep_kernel<<<64 + OUT_, 256, 0, stream>>>(x, xTbf, mask, cnt, idx);
    spmm_mfma<<<OUT_ * 2, 512, 0, stream>>>(xTbf, peso, cnt, idx, out);
}